// Round 10
// baseline (4565.376 us; speedup 1.0000x reference)
//
#include <hip/hip_runtime.h>
#include <cstdint>
#include <cstddef>

// B=256, T=512, D=64, H=256, G=1024. Two-layer LSTM + FC.
// R10 = proven-best compound: R5 gemm (gi-major scatter, merged stores)
// + R7 rec (kf0-1 LDS, kf2-7 depth-2 L2 stream, intrinsic MFMA, 128 VGPR)
// + ONE change: rotated refill map (2->4,3->5,4->6,5->7,6->2,7->3) so the
// kf2/kf3 loads for step t+1 issue BEFORE the cell phase/barrier and their
// L2 latency hides under ~1700 cyc of cell VALU instead of stalling step-top.
// R8 (cross-CU exchange: 96 MB/dispatch HBM sync tax) and R9 (inline-asm
// AGPR MFMA: hazard-unsafe, absmax 3.8e-3) are abandoned with evidence.
#define GATES 1024
#define SEQT  512
#define TCH   32
#define NCH   16
#define XPSTEP 262144   // elements per timestep in rec-order xp: 16*512*32

using u16 = unsigned short;
using bf16x8 = __attribute__((ext_vector_type(8))) short;   // 8 bf16 = 4 VGPRs
using f32x4  = __attribute__((ext_vector_type(4))) float;

__device__ __forceinline__ float bf2f(u16 u) {
    union { float f; unsigned int i; } v; v.i = ((unsigned int)u) << 16; return v.f;
}
__device__ __forceinline__ u16 f2bf(float f) {
    union { float f; unsigned int i; } v; v.f = f;
    unsigned int r = v.i + 0x7FFFu + ((v.i >> 16) & 1u);   // RNE
    return (u16)(r >> 16);
}
// overflow-safe fast activations (v_exp + v_rcp, ~1 ulp)
__device__ __forceinline__ float sigm(float x) {
    return __builtin_amdgcn_rcpf(1.f + __expf(-x));
}
__device__ __forceinline__ float tanh_f(float x) {
    return 1.f - 2.f * __builtin_amdgcn_rcpf(1.f + __expf(2.f * x));
}

// ---------------- prep ----------------
__global__ void k_conv(const float* __restrict__ src, u16* __restrict__ dst, int n) {
    int i = blockIdx.x * 256 + threadIdx.x;
    if (i < n) dst[i] = f2bf(src[i]);
}
__global__ void k_bias(const float* __restrict__ a, const float* __restrict__ b,
                       float* __restrict__ o, int n) {
    int i = blockIdx.x * 256 + threadIdx.x;
    if (i < n) o[i] = a[i] + b[i];
}

// ---------------- fused input-projection GEMM (R5 epilogue, proven) --------
// blocks 0-511: layer0 (A=xb [256][512][64], K=64); 512-1023: layer1 (A=h0c).
//   el = ((tloc*16+blk)*512 + w*64 + qr*16 + mlr)*32 + gi*8 + s*4 + r_r
__global__ __launch_bounds__(256, 2) void gemm_fused(
    const u16* __restrict__ A0, const u16* __restrict__ W0,
    const float* __restrict__ b0, u16* __restrict__ o0, int t00,
    const u16* __restrict__ A1, const u16* __restrict__ W1,
    const float* __restrict__ b1, u16* __restrict__ o1, int it)
{
    const int half = blockIdx.x >> 9;
    if (half == 0 && it >= NCH) return;
    if (half == 1 && it == 0) return;
    const int bid = blockIdx.x & 511;

    const u16* A; const u16* W; const float* bias; u16* out;
    int K, As_b, As_t, t0;
    if (half == 0) { A = A0; W = W0; bias = b0; out = o0; K = 64;  As_b = 32768; As_t = 64;    t0 = t00; }
    else           { A = A1; W = W1; bias = b1; out = o1; K = 256; As_b = 256;   As_t = 65536; t0 = 0;   }

    __shared__ __align__(16) u16 As[128][40];
    __shared__ __align__(16) u16 Bs[128][40];
    const int tid  = threadIdx.x;
    const int mb   = bid >> 3, nb = bid & 7;
    const int n0   = nb * 128;
    const int wave = tid >> 6, lane = tid & 63;
    const int wm   = wave >> 1, wn = wave & 1;
    const int ml   = lane & 15, q = lane >> 4;
    const int tloc = mb >> 1;
    const int tt   = t0 + tloc;
    const int bbas = (mb & 1) * 128;

    f32x4 acc[4][4];
    #pragma unroll
    for (int mi = 0; mi < 4; ++mi)
        #pragma unroll
        for (int ni = 0; ni < 4; ++ni)
            acc[mi][ni] = (f32x4)0.f;

    const int nk = K >> 5;
    for (int kt = 0; kt < nk; ++kt) {
        __syncthreads();
        #pragma unroll
        for (int i = 0; i < 2; ++i) {
            int c = tid + i * 256;
            int row = c >> 2, kb = c & 3;
            *(uint4*)&As[row][kb * 8] = *(const uint4*)(
                A + (size_t)(bbas + row) * As_b + (size_t)tt * As_t + kt * 32 + kb * 8);
            *(uint4*)&Bs[row][kb * 8] = *(const uint4*)(
                W + (size_t)(n0 + row) * K + kt * 32 + kb * 8);
        }
        __syncthreads();
        bf16x8 af[4], bfr[4];
        #pragma unroll
        for (int mi = 0; mi < 4; ++mi)
            af[mi] = *(const bf16x8*)&As[wm * 64 + mi * 16 + ml][q * 8];
        #pragma unroll
        for (int ni = 0; ni < 4; ++ni)
            bfr[ni] = *(const bf16x8*)&Bs[wn * 64 + ni * 16 + ml][q * 8];
        #pragma unroll
        for (int mi = 0; mi < 4; ++mi)
            #pragma unroll
            for (int ni = 0; ni < 4; ++ni)
                acc[mi][ni] = __builtin_amdgcn_mfma_f32_16x16x32_bf16(
                    af[mi], bfr[ni], acc[mi][ni], 0, 0, 0);
    }

    #pragma unroll
    for (int ni = 0; ni < 4; ++ni) {
        int gc = n0 + wn * 64 + ni * 16 + ml;
        int gi = gc >> 8, u = gc & 255;
        int w = u >> 5, s = (u >> 4) & 1, mlr = u & 15;
        float bv = bias[gc];
        #pragma unroll
        for (int mi = 0; mi < 4; ++mi) {
            int b0r = bbas + wm * 64 + mi * 16 + q * 4;
            #pragma unroll
            for (int rr = 0; rr < 4; ++rr) {
                int bb = b0r + rr;
                int blk = bb >> 4, qr = (bb >> 2) & 3, r_r = bb & 3;
                size_t el = ((size_t)((tloc * 16 + blk) * 512 + w * 64 + qr * 16 + mlr)) * 32
                            + gi * 8 + s * 4 + r_r;
                out[el] = f2bf(acc[mi][ni][rr] + bv);
            }
        }
    }
}

// ---------------- fused LSTM recurrence (R7 + cross-barrier prefetch) ------
// Blocks 0-15: layer0 chunk it; 16-31: layer1 chunk it-1. Wave owns 128 gate
// rows. W: kf0-1 from LDS (staged once); kf2-7 streamed from L2 via depth-2
// wbuf[2][8] with ROTATED refill (k -> k+2 mod {2..7}): the kf2/kf3 loads for
// step t+1 issue before the cell phase, landing under cell VALU + barrier.
__global__ __launch_bounds__(512, 2) void lstm_rec2(
    const u16* __restrict__ xp0, const u16* __restrict__ xp1,
    const u16* __restrict__ W0,  const u16* __restrict__ W1,
    u16* __restrict__ h0c, float* __restrict__ hlast,
    u16* __restrict__ hs0, float* __restrict__ cs0,
    u16* __restrict__ hs1, float* __restrict__ cs1, int it)
{
    const int L   = blockIdx.x >> 4;
    const int blk = blockIdx.x & 15;
    if (L == 0 && it >= NCH) return;
    if (L == 1 && it == 0) return;
    const int chunk = L ? it - 1 : it;
    const u16* xp = L ? xp1 : xp0;
    const u16* W  = L ? W1 : W0;
    u16*  hs = L ? hs1 : hs0;
    float* cs = L ? cs1 : cs0;
    const int init = (chunk == 0);

    __shared__ __align__(16) u16 WL[65536];          // 131072 B: kf0-1 frag-order
    __shared__ __align__(16) u16 hA[2][16][264];     // 16896 B double buffer

    const int tid  = threadIdx.x;
    const int wave = tid >> 6, lane = tid & 63;
    const int ml   = lane & 15, q = lane >> 4;
    const int ub   = wave * 32;
    const int bb0  = blk * 16;

    // W fragment element offsets: frag f = gi*2+s -> gate rows g
    int woff_[8];
    #pragma unroll
    for (int gi = 0; gi < 4; ++gi)
        #pragma unroll
        for (int s = 0; s < 2; ++s)
            woff_[gi * 2 + s] = (gi * 256 + ub + s * 16 + ml) * 256 + q * 8;

    // stage kf0-1 into LDS (per-wave region, 16 B contiguous per lane/slot)
    const int wlb = (wave * 1024 + lane) * 8;
    #pragma unroll
    for (int kf = 0; kf < 2; ++kf)
        #pragma unroll
        for (int f = 0; f < 8; ++f)
            *(bf16x8*)&WL[wlb + (kf * 8 + f) * 512] =
                *(const bf16x8*)(W + woff_[f] + kf * 32);

    float c_[8];
    if (init) {
        for (int i = tid; i < 16 * 264; i += 512) ((u16*)&hA[0][0][0])[i] = 0;
        #pragma unroll
        for (int i = 0; i < 8; ++i) c_[i] = 0.f;
    } else {
        int m = tid >> 5, j0 = (tid & 31) * 8;
        *(bf16x8*)&hA[0][m][j0] = *(const bf16x8*)&hs[(size_t)(bb0 + m) * 256 + j0];
        #pragma unroll
        for (int s = 0; s < 2; ++s)
            #pragma unroll
            for (int r = 0; r < 4; ++r)
                c_[s * 4 + r] = cs[(size_t)(bb0 + q * 4 + r) * 256 + ub + s * 16 + ml];
    }

    const u16* xpl = xp + ((size_t)blk * 512 + tid) * 32;   // + XPSTEP per step

    // stream prologue: kf2 -> wbuf[0], kf3 -> wbuf[1] (for step 0)
    bf16x8 wbuf[2][8];
    #pragma unroll
    for (int f = 0; f < 8; ++f)
        wbuf[0][f] = *(const bf16x8*)(W + woff_[f] + 2 * 32);
    #pragma unroll
    for (int f = 0; f < 8; ++f)
        wbuf[1][f] = *(const bf16x8*)(W + woff_[f] + 3 * 32);

    __syncthreads();

    for (int t = 0; t < TCH; ++t) {
        const int br = t & 1, bw = br ^ 1;

        // xp for this step: 4x16B, in flight across the K-loop
        bf16x8 xv[4];
        #pragma unroll
        for (int j = 0; j < 4; ++j)
            xv[j] = *(const bf16x8*)(xpl + j * 8);

        f32x4 acc[4][2];
        #pragma unroll
        for (int gi = 0; gi < 4; ++gi)
            #pragma unroll
            for (int s = 0; s < 2; ++s)
                acc[gi][s] = (f32x4)0.f;

        // kf0-1 from LDS
        #pragma unroll
        for (int kf = 0; kf < 2; ++kf) {
            bf16x8 a = *(const bf16x8*)&hA[br][ml][kf * 32 + q * 8];
            #pragma unroll
            for (int f = 0; f < 8; ++f) {
                bf16x8 b = *(const bf16x8*)&WL[wlb + (kf * 8 + f) * 512];
                acc[f >> 1][f & 1] = __builtin_amdgcn_mfma_f32_16x16x32_bf16(
                    a, b, acc[f >> 1][f & 1], 0, 0, 0);
            }
        }
        // kf2-7: consume wbuf[k&1], refill with k+2 (rotating into next step:
        // k=6 refills kf2, k=7 refills kf3 -> land during cell phase/barrier)
        #pragma unroll
        for (int k = 2; k < 8; ++k) {
            bf16x8 a = *(const bf16x8*)&hA[br][ml][k * 32 + q * 8];
            #pragma unroll
            for (int f = 0; f < 8; ++f)
                acc[f >> 1][f & 1] = __builtin_amdgcn_mfma_f32_16x16x32_bf16(
                    a, wbuf[k & 1][f], acc[f >> 1][f & 1], 0, 0, 0);
            const int kn = (k + 2 < 8) ? k + 2 : k - 4;
            #pragma unroll
            for (int f = 0; f < 8; ++f)
                wbuf[k & 1][f] = *(const bf16x8*)(W + woff_[f] + kn * 32);
        }

        // cell phase: pre-activation = acc + xp (bias folded into xp)
        #pragma unroll
        for (int s = 0; s < 2; ++s) {
            int j = ub + s * 16 + ml;
            #pragma unroll
            for (int r = 0; r < 4; ++r) {
                int m = q * 4 + r;
                float ig = sigm(acc[0][s][r] + bf2f((u16)xv[0][s * 4 + r]));
                float fg = sigm(acc[1][s][r] + bf2f((u16)xv[1][s * 4 + r]));
                float gg = tanh_f(acc[2][s][r] + bf2f((u16)xv[2][s * 4 + r]));
                float og = sigm(acc[3][s][r] + bf2f((u16)xv[3][s * 4 + r]));
                float cc = fg * c_[s * 4 + r] + ig * gg;
                c_[s * 4 + r] = cc;
                float h = og * tanh_f(cc);
                u16 hb = f2bf(h);
                hA[bw][m][j] = hb;
                if (L == 0)
                    h0c[((size_t)t * 256 + bb0 + m) * 256 + j] = hb;
                else if (chunk == NCH - 1 && t == TCH - 1)
                    hlast[(size_t)(bb0 + m) * 256 + j] = h;
            }
        }
        xpl += XPSTEP;
        __syncthreads();   // h(t+1) published in buf bw
    }

    // persist state (TCH even -> final h in buf 0)
    #pragma unroll
    for (int s = 0; s < 2; ++s)
        #pragma unroll
        for (int r = 0; r < 4; ++r)
            cs[(size_t)(bb0 + q * 4 + r) * 256 + ub + s * 16 + ml] = c_[s * 4 + r];
    {
        int m = tid >> 5, j0 = (tid & 31) * 8;
        *(bf16x8*)&hs[(size_t)(bb0 + m) * 256 + j0] = *(const bf16x8*)&hA[0][m][j0];
    }
}

// ---------------- FC head ----------------
__global__ void fc_k(const float* __restrict__ h, const float* __restrict__ w,
                     const float* __restrict__ b, float* __restrict__ out)
{
    int bb = blockIdx.x, lane = threadIdx.x;
    float s = 0.f;
    for (int j = lane; j < 256; j += 64) s += h[bb * 256 + j] * w[j];
    #pragma unroll
    for (int off = 32; off > 0; off >>= 1) s += __shfl_down(s, off);
    if (lane == 0) out[bb] = s + b[0];
}

extern "C" void kernel_launch(void* const* d_in, const int* in_sizes, int n_in,
                              void* d_out, int out_size, void* d_ws, size_t ws_size,
                              hipStream_t stream)
{
    const float* x    = (const float*)d_in[0];
    const float* Wih0 = (const float*)d_in[1];
    const float* Whh0 = (const float*)d_in[2];
    const float* bih0 = (const float*)d_in[3];
    const float* bhh0 = (const float*)d_in[4];
    const float* Wih1 = (const float*)d_in[5];
    const float* Whh1 = (const float*)d_in[6];
    const float* bih1 = (const float*)d_in[7];
    const float* bhh1 = (const float*)d_in[8];
    const float* fcw  = (const float*)d_in[9];
    const float* fcb  = (const float*)d_in[10];
    float* out = (float*)d_out;

    // workspace layout, total ~57.3 MB
    char* ws = (char*)d_ws;
    u16*   xp0   = (u16*)(ws);                  // 16777216
    u16*   xp1   = (u16*)(ws + 16777216);       // 16777216
    u16*   h0c   = (u16*)(ws + 33554432);       //  4194304  [32][256][256] bf16
    u16*   xb    = (u16*)(ws + 37748736);       // 16777216  [256][512][64] bf16
    u16*   Wih0b = (u16*)(ws + 54525952);       //   131072
    u16*   Whh0b = (u16*)(ws + 54657024);       //   524288
    u16*   Wih1b = (u16*)(ws + 55181312);       //   524288
    u16*   Whh1b = (u16*)(ws + 55705600);       //   524288
    float* bias0 = (float*)(ws + 56229888);     //     4096
    float* bias1 = (float*)(ws + 56233984);     //     4096
    u16*   hs0   = (u16*)(ws + 56238080);       //   131072
    float* cs0   = (float*)(ws + 56369152);     //   262144
    u16*   hs1   = (u16*)(ws + 56631296);       //   131072
    float* cs1   = (float*)(ws + 56762368);     //   262144
    float* h1l   = (float*)(ws + 57024512);     //   262144

    k_conv<<<32768, 256, 0, stream>>>(x, xb, 8388608);
    k_conv<<<256,   256, 0, stream>>>(Wih0, Wih0b, 65536);
    k_conv<<<1024,  256, 0, stream>>>(Whh0, Whh0b, 262144);
    k_conv<<<1024,  256, 0, stream>>>(Wih1, Wih1b, 262144);
    k_conv<<<1024,  256, 0, stream>>>(Whh1, Whh1b, 262144);
    k_bias<<<4, 256, 0, stream>>>(bih0, bhh0, bias0, 1024);
    k_bias<<<4, 256, 0, stream>>>(bih1, bhh1, bias1, 1024);

    for (int it = 0; it <= NCH; ++it) {
        gemm_fused<<<1024, 256, 0, stream>>>(xb, Wih0b, bias0, xp0, it * TCH,
                                             h0c, Wih1b, bias1, xp1, it);
        lstm_rec2<<<32, 512, 0, stream>>>(xp0, xp1, Whh0b, Whh1b, h0c, h1l,
                                          hs0, cs0, hs1, cs1, it);
    }
    fc_k<<<256, 64, 0, stream>>>(h1l, fcw, fcb, out);
}